// Round 11
// baseline (3833.141 us; speedup 1.0000x reference)
//
#include <hip/hip_runtime.h>
#include <hip/hip_bf16.h>

typedef unsigned int u32;
typedef unsigned short u16;
typedef short s16x8 __attribute__((ext_vector_type(8)));   // 8 bf16 (4 VGPR) MFMA A/B frag
typedef float f32x4 __attribute__((ext_vector_type(4)));   // MFMA acc
typedef u16 u16x4 __attribute__((ext_vector_type(4)));

__device__ __forceinline__ u16 f2b(float x) {              // RTNE fp32->bf16
  u32 u = __float_as_uint(x);
  return (u16)((u + 0x7fffu + ((u >> 16) & 1u)) >> 16);
}
__device__ __forceinline__ float b2f(u16 x) { return __uint_as_float(((u32)x) << 16); }

__device__ __forceinline__ void gload16(const void* g, void* l) {
  __builtin_amdgcn_global_load_lds((const __attribute__((address_space(1))) u32*)g,
                                   (__attribute__((address_space(3))) u32*)l, 16, 0, 0);
}
__device__ __forceinline__ f32x4 mfma16(s16x8 a, s16x8 b, f32x4 c) {
  return __builtin_amdgcn_mfma_f32_16x16x32_bf16(a, b, c, 0, 0, 0);
}

// ---------------------------------------------------------------------------
// gemm256 v6 = round-4 2-phase body (BK=32, 64 KB LDS dbuf — proven 380 µs)
// + T1 XCD remap + __launch_bounds__(512, 4).
// KEY CHANGE: launch_bounds 2nd arg is min waves/EU; for 512-thr blocks
// k = w*4/8, so the old (512,2) declared 1 block/CU — the barrier-lockstep
// had no co-resident block to overlap with (m114 mechanism). (512,4) = 2
// blocks/CU (16 waves/CU): block A's barrier/lgkm drains overlap block B's
// MFMA bursts. LDS 2x64=128<=160 OK; unified regs ~240 < 512/wave cap OK.
// WAR (proven round 4): reads of buf[t&1] all issued before first MFMA half;
// lgkm0+barrier drains them chip-wide; stage(t+2) into buf[t&1] after that.
// vmcnt(4) at iter top keeps t+1's 4 loads in flight; last iter vmcnt(0).
// Swizzle: same involution (byte ^ ((byte>>7)&7)<<4) on pre-swizzled global
// source and ds_read addr; 0 bank conflicts measured (round 4).
// ---------------------------------------------------------------------------
template <int OUT_BF16>
__global__ __launch_bounds__(512, 4) void gemm256(
    const u16* __restrict__ A, long long sA, int lda,
    const u16* __restrict__ B1, long long sB1, int K1,
    const u16* __restrict__ B2, long long sB2, int K2,
    void* __restrict__ Cv, long long sC, int ldc,
    const float* __restrict__ bias, int bias_mode,  // 0 none, 1 per-col, 2 per-row
    int relu_limit, float alpha) {
  const int K = K1 + K2, nt = K >> 5;
  // T1: xcd = flat%8; b=xcd, tm-fastest within xcd for B-panel L2 reuse.
  int tm, tn, b;
  {
    const int flat = blockIdx.x + gridDim.x * (blockIdx.y + gridDim.y * blockIdx.z);
    if (gridDim.z == 8) {
      const int slot = flat >> 3;
      b = flat & 7;
      tm = slot % gridDim.x;
      tn = slot / gridDim.x;
    } else { tm = blockIdx.x; tn = blockIdx.y; b = blockIdx.z; }
  }
  const u16* Ab = A + (size_t)b * sA + (size_t)tm * 256 * lda;
  const u16* B1b = B1 + (size_t)b * sB1 + (size_t)tn * 256 * K1;
  const u16* B2b = B2 ? (B2 + (size_t)b * sB2 + (size_t)tn * 256 * K2) : (const u16*)0;

  __shared__ u16 lds[32768];   // [2 buf][A 8192 | B 8192 elems] = 64 KB

  const int tt = threadIdx.x, w = tt >> 6, l = tt & 63;
  const int wr = w >> 2, wc = w & 3;

  // staging: inst i stages 16B/lane; lane's linear tile byte lin=(i*512+tt)*16;
  // source fetches tile-offset swz(lin) so LDS[swz(x)] holds T[x].
  int sx[2], sdst[2];
#pragma unroll
  for (int i = 0; i < 2; ++i) {
    const int lin = (i * 512 + tt) << 4;
    sx[i] = lin ^ (((lin >> 7) & 7) << 4);
    sdst[i] = (i * 512 + w * 64) << 3;   // wave-uniform dest base (elems)
  }

  auto stage = [&](int kt) {
    const int buf = (kt & 1) << 14;
    const int kk = kt << 5;
#pragma unroll
    for (int i = 0; i < 2; ++i) {
      const int x = sx[i];
      gload16(Ab + (size_t)(x >> 6) * lda + kk + ((x & 63) >> 1), &lds[buf + sdst[i]]);
    }
    const u16* Bb; int ld, kloc;
    if (kk < K1) { Bb = B1b; ld = K1; kloc = kk; }
    else         { Bb = B2b; ld = K2; kloc = kk - K1; }
#pragma unroll
    for (int i = 0; i < 2; ++i) {
      const int x = sx[i];
      gload16(Bb + (size_t)(x >> 6) * ld + kloc + ((x & 63) >> 1), &lds[buf + 8192 + sdst[i]]);
    }
  };

  stage(0);
  if (nt > 1) stage(1);

  f32x4 acc[8][4] = {};
  const int lr = l & 15, lk16 = (l >> 4) << 4;

  for (int t = 0; t < nt; ++t) {
    const int buf = (t & 1) << 14;
    if (t == nt - 1) asm volatile("s_waitcnt vmcnt(0)" ::: "memory");
    else             asm volatile("s_waitcnt vmcnt(4)" ::: "memory");
    __builtin_amdgcn_s_barrier();

    const char* Abuf = (const char*)&lds[buf];
    const char* Bbuf = (const char*)&lds[buf + 8192];
    s16x8 bfr[4], af[8];
#pragma unroll
    for (int j = 0; j < 4; ++j) {
      const int lin = ((wc * 64 + j * 16 + lr) << 6) | lk16;
      bfr[j] = *reinterpret_cast<const s16x8*>(Bbuf + (lin ^ (((lin >> 7) & 7) << 4)));
    }
#pragma unroll
    for (int m = 0; m < 8; ++m) {
      const int lin = ((wr * 128 + m * 16 + lr) << 6) | lk16;
      af[m] = *reinterpret_cast<const s16x8*>(Abuf + (lin ^ (((lin >> 7) & 7) << 4)));
    }
    __builtin_amdgcn_s_setprio(1);
#pragma unroll
    for (int m = 0; m < 4; ++m)
#pragma unroll
      for (int j = 0; j < 4; ++j)
        acc[m][j] = mfma16(af[m], bfr[j], acc[m][j]);
    __builtin_amdgcn_s_setprio(0);

    asm volatile("s_waitcnt lgkmcnt(0)" ::: "memory");   // all 12 ds_reads retired
    __builtin_amdgcn_s_barrier();                        // ...chip-wide: race gate
    if (t + 2 < nt) stage(t + 2);                        // overwrite buf[cur] safely

    __builtin_amdgcn_s_setprio(1);
#pragma unroll
    for (int m = 4; m < 8; ++m)
#pragma unroll
      for (int j = 0; j < 4; ++j)
        acc[m][j] = mfma16(af[m], bfr[j], acc[m][j]);
    __builtin_amdgcn_s_setprio(0);
  }

  const int li = (l >> 4) * 4;
#pragma unroll
  for (int m = 0; m < 8; ++m) {
    const int row = tm * 256 + wr * 128 + m * 16 + li;
#pragma unroll
    for (int j = 0; j < 4; ++j) {
      const int col = tn * 256 + wc * 64 + j * 16 + lr;
      const float bc = (bias_mode == 1) ? bias[col] : 0.f;
#pragma unroll
      for (int i = 0; i < 4; ++i) {
        float v = acc[m][j][i] * alpha;
        v += (bias_mode == 2) ? bias[row + i] : bc;
        if (col < relu_limit) v = fmaxf(v, 0.f);
        const size_t idx = (size_t)b * sC + (size_t)(row + i) * ldc + col;
        if (OUT_BF16) ((u16*)Cv)[idx] = f2b(v);
        else          ((float*)Cv)[idx] = v;
      }
    }
  }
}

// ---------------------------------------------------------------------------
// m97-structure 128x128 GEMM (W_comb, q).
// ---------------------------------------------------------------------------
template <int OUT_BF16>
__global__ __launch_bounds__(256) void gemm_bt(
    const u16* __restrict__ A, long long sA, int lda,
    const u16* __restrict__ B1, long long sB1, int K1,
    const u16* __restrict__ B2, long long sB2, int K2,
    void* __restrict__ Cv, long long sC, int ldc,
    const float* __restrict__ bias, int bias_mode,
    int relu_limit, float alpha) {
  const int K = K1 + K2;
  const int b = blockIdx.z;
  const int tm = blockIdx.x, tn = blockIdx.y;
  const u16* Ab = A + (size_t)b * sA;
  const u16* B1b = B1 + (size_t)b * sB1;
  const u16* B2b = B2 ? (B2 + (size_t)b * sB2) : (const u16*)0;

  __shared__ u16 As[128 * 32];
  __shared__ u16 Bs[128 * 32];

  const int t = threadIdx.x;
  const int w = t >> 6, l = t & 63;
  const int wr = w >> 1, wc = w & 1;
  const int srow = w * 16 + (l >> 2);
  const int scol = (l & 3) * 8;
  u16* AsW = As + w * 512;
  u16* BsW = Bs + w * 512;

  f32x4 acc[4][4] = {};
  const int lr = l & 15, lk = (l >> 4) * 8;

  for (int kk = 0; kk < K; kk += 32) {
    __syncthreads();
    {
      const u16* g0 = Ab + (size_t)(tm * 128 + srow) * lda + (kk + scol);
      gload16(g0, AsW);
      gload16(g0 + (size_t)64 * lda, AsW + 2048);
    }
    {
      const u16* bb; int ld, kloc;
      if (kk < K1) { bb = B1b; ld = K1; kloc = kk; }
      else         { bb = B2b; ld = K2; kloc = kk - K1; }
      const u16* g0 = bb + (size_t)(tn * 128 + srow) * ld + (kloc + scol);
      gload16(g0, BsW);
      gload16(g0 + (size_t)64 * ld, BsW + 2048);
    }
    __syncthreads();
    s16x8 af[4], bfr[4];
#pragma unroll
    for (int m = 0; m < 4; ++m)
      af[m] = *reinterpret_cast<const s16x8*>(&As[(wr * 64 + m * 16 + lr) * 32 + lk]);
#pragma unroll
    for (int j = 0; j < 4; ++j)
      bfr[j] = *reinterpret_cast<const s16x8*>(&Bs[(wc * 64 + j * 16 + lr) * 32 + lk]);
#pragma unroll
    for (int m = 0; m < 4; ++m)
#pragma unroll
      for (int j = 0; j < 4; ++j)
        acc[m][j] = mfma16(af[m], bfr[j], acc[m][j]);
  }

  const int li = (l >> 4) * 4;
#pragma unroll
  for (int m = 0; m < 4; ++m) {
    const int row = tm * 128 + wr * 64 + m * 16 + li;
#pragma unroll
    for (int j = 0; j < 4; ++j) {
      const int col = tn * 128 + wc * 64 + j * 16 + lr;
      const float bc = (bias_mode == 1) ? bias[col] : 0.f;
#pragma unroll
      for (int i = 0; i < 4; ++i) {
        float v = acc[m][j][i] * alpha;
        v += (bias_mode == 2) ? bias[row + i] : bc;
        if (col < relu_limit) v = fmaxf(v, 0.f);
        const size_t idx = (size_t)b * sC + (size_t)(row + i) * ldc + col;
        if (OUT_BF16) ((u16*)Cv)[idx] = f2b(v);
        else          ((float*)Cv)[idx] = v;
      }
    }
  }
}

// ---------------------------------------------------------------------------
// attn_fused: sim + softmax + PV in one kernel (verified round 9).
// ---------------------------------------------------------------------------
__global__ __launch_bounds__(512) void attn_fused(
    const u16* __restrict__ qT,   // [8][4096][256] bf16
    const u16* __restrict__ Kp,   // [8][128][256] bf16 (rows>=110 zero)
    const u16* __restrict__ Vp,   // [8][256][128] bf16
    u16* __restrict__ ctxT) {     // [8][4096][256] bf16
  const int qb = blockIdx.x, b = blockIdx.y;
  const int tt = threadIdx.x, w = tt >> 6, l = tt & 63;
  const int lr = l & 15, hi = l >> 4;
  __shared__ __attribute__((aligned(128))) char lds[131072];

  const char* KpG = (const char*)(Kp + (size_t)b * 32768);
  const char* VpG = (const char*)(Vp + (size_t)b * 32768);
#pragma unroll
  for (int g = 0; g < 8; ++g) {
    const int lin = (g * 512 + tt) << 4;
    gload16(KpG + (lin ^ (((lin >> 9) & 7) << 4)), lds + g * 8192 + w * 1024);
  }
#pragma unroll
  for (int g = 0; g < 8; ++g) {
    const int lin = (g * 512 + tt) << 4;
    gload16(VpG + (lin ^ (((lin >> 8) & 7) << 4)), lds + 65536 + g * 8192 + w * 1024);
  }

  const u16* qG = qT + ((size_t)b * 4096 + qb * 128 + w * 16 + lr) * 256 + hi * 8;
  s16x8 qf[8];
#pragma unroll
  for (int kk = 0; kk < 8; ++kk)
    qf[kk] = *reinterpret_cast<const s16x8*>(qG + kk * 32);

  asm volatile("s_waitcnt vmcnt(0)" ::: "memory");
  __syncthreads();

  f32x4 ps[8] = {};
  for (int kk = 0; kk < 8; ++kk) {
#pragma unroll
    for (int j = 0; j < 8; ++j) {
      const int y = (j * 16 + lr) * 512 + kk * 64 + hi * 16;
      const s16x8 kf = *reinterpret_cast<const s16x8*>(lds + (y ^ (((y >> 9) & 7) << 4)));
      ps[j] = mfma16(qf[kk], kf, ps[j]);
    }
  }
  __syncthreads();   // all waves done reading Kp region before P overwrites it

#pragma unroll
  for (int i = 0; i < 4; ++i) {
    float m0 = -1e30f;
#pragma unroll
    for (int j = 0; j < 7; ++j) {
      float v = ps[j][i] * 0.0625f;
      if (j == 6 && lr >= 14) v = -1e30f;
      m0 = fmaxf(m0, v);
    }
#pragma unroll
    for (int off = 8; off; off >>= 1) m0 = fmaxf(m0, __shfl_xor(m0, off, 16));
    float s0 = 0.f;
#pragma unroll
    for (int j = 0; j < 7; ++j) {
      const float v = ps[j][i] * 0.0625f;
      const float ev = (j == 6 && lr >= 14) ? 0.f : __expf(v - m0);
      ps[j][i] = ev;
      s0 += ev;
    }
    ps[7][i] = 0.f;
#pragma unroll
    for (int off = 8; off; off >>= 1) s0 += __shfl_xor(s0, off, 16);
    const float inv = 1.f / s0;
#pragma unroll
    for (int j = 0; j < 8; ++j) ps[j][i] *= inv;
  }

  char* PL = lds + w * 4096;
#pragma unroll
  for (int j = 0; j < 8; ++j)
#pragma unroll
    for (int i = 0; i < 4; ++i) {
      const int n = hi * 4 + i, m = j * 16 + lr;
      const int y = n * 256 + m * 2;
      *reinterpret_cast<u16*>(PL + (y ^ ((n & 7) << 4))) = f2b(ps[j][i]);
    }
  __syncthreads();

  f32x4 pc[16] = {};
  const char* VL = lds + 65536;
#pragma unroll
  for (int kk = 0; kk < 4; ++kk) {
    const int ya = lr * 256 + kk * 64 + hi * 16;
    const s16x8 pa = *reinterpret_cast<const s16x8*>(PL + (ya ^ ((lr & 7) << 4)));
#pragma unroll
    for (int jc = 0; jc < 16; ++jc) {
      const int y = (jc * 16 + lr) * 256 + kk * 64 + hi * 16;
      const s16x8 vf = *reinterpret_cast<const s16x8*>(VL + (y ^ (((y >> 8) & 7) << 4)));
      pc[jc] = mfma16(pa, vf, pc[jc]);
    }
  }

  u16* outp = ctxT + ((size_t)b * 4096 + qb * 128 + w * 16) * 256;
#pragma unroll
  for (int jc = 0; jc < 16; ++jc)
#pragma unroll
    for (int i = 0; i < 4; ++i)
      outp[(size_t)(hi * 4 + i) * 256 + jc * 16 + lr] = f2b(pc[jc][i]);
}

// [b][R][C] fp32 -> [b][C][R] bf16 ; R,C multiples of 64
__global__ __launch_bounds__(256) void transpose_cvt(
    const float* __restrict__ in, u16* __restrict__ out, int R, int C) {
  const int b = blockIdx.z;
  in += (size_t)b * R * C;
  out += (size_t)b * R * C;
  const int ct = blockIdx.x, rt = blockIdx.y;
  __shared__ float tile[64][65];
  const int t = threadIdx.x;
  {
    const int c4 = (t & 15) * 4, r0 = t >> 4;
    const float* src = in + (size_t)(rt * 64 + r0) * C + ct * 64 + c4;
#pragma unroll
    for (int i = 0; i < 4; ++i) {
      const float4 v = *reinterpret_cast<const float4*>(src + (size_t)(i * 16) * C);
      tile[r0 + i * 16][c4 + 0] = v.x; tile[r0 + i * 16][c4 + 1] = v.y;
      tile[r0 + i * 16][c4 + 2] = v.z; tile[r0 + i * 16][c4 + 3] = v.w;
    }
  }
  __syncthreads();
  {
    const int r4 = (t & 15) * 4, c0 = t >> 4;
    u16* dst = out + (size_t)(ct * 64 + c0) * R + rt * 64 + r4;
#pragma unroll
    for (int i = 0; i < 4; ++i) {
      u16x4 o;
      o.x = f2b(tile[r4 + 0][c0 + i * 16]);
      o.y = f2b(tile[r4 + 1][c0 + i * 16]);
      o.z = f2b(tile[r4 + 2][c0 + i * 16]);
      o.w = f2b(tile[r4 + 3][c0 + i * 16]);
      *reinterpret_cast<u16x4*>(dst + (size_t)(i * 16) * R) = o;
    }
  }
}

// folded-BN weight preps -------------------------------------------------------
__global__ __launch_bounds__(256) void prep_wq(const float* __restrict__ qw,
    const float* __restrict__ qg, const float* __restrict__ qb_,
    const float* __restrict__ qm, const float* __restrict__ qv,
    u16* __restrict__ Wq, float* __restrict__ qbias) {
  const int i = blockIdx.x * 256 + threadIdx.x;  // 256*2048
  const int o = i >> 11, c = i & 2047;
  const float inv = qg[o] * rsqrtf(qv[o] + 1e-5f);
  Wq[i] = f2b(qw[i] * inv);
  if (c == 0) qbias[o] = qb_[o] - qm[o] * inv;
}

__global__ __launch_bounds__(256) void prep_wkv(const float* __restrict__ kw,
    const float* __restrict__ kg, const float* __restrict__ kb,
    const float* __restrict__ km, const float* __restrict__ kv,
    const float* __restrict__ vw, const float* __restrict__ vb,
    u16* __restrict__ Wkv, float* __restrict__ kvbias) {
  const int i = blockIdx.x * 256 + threadIdx.x;  // 512*1024
  const int r = i >> 10, c = i & 1023;
  if (r < 256) {
    const float inv = kg[r] * rsqrtf(kv[r] + 1e-5f);
    Wkv[i] = f2b(kw[i] * inv);
    if (c == 0) kvbias[r] = kb[r] - km[r] * inv;
  } else {
    Wkv[i] = f2b(vw[(size_t)(r - 256) * 1024 + c]);
    if (c == 0) kvbias[r] = vb[r - 256];
  }
}

__global__ __launch_bounds__(256) void prep_bn(const float* __restrict__ bn_w,
    const float* __restrict__ g, const float* __restrict__ v_,
    u16* __restrict__ bn1s, u16* __restrict__ Wfin) {
  const int i = blockIdx.x * 256 + threadIdx.x;  // 2048*2048
  const int o = i >> 11, j = i & 2047;
  const float inv = g[o] * rsqrtf(v_[o] + 1e-5f);
  bn1s[i] = f2b(bn_w[(size_t)o * 4096 + j] * inv);
  Wfin[(size_t)o * 2304 + j] = f2b(bn_w[(size_t)o * 4096 + 2048 + j] * inv);
}

__global__ __launch_bounds__(256) void prep_fbias(const float* __restrict__ bn_w,
    const float* __restrict__ o_b, const float* __restrict__ g,
    const float* __restrict__ bb, const float* __restrict__ m_,
    const float* __restrict__ v_, float* __restrict__ fbias) {
  const int o = blockIdx.x, t = threadIdx.x;
  float s = 0.f;
  for (int j = t; j < 2048; j += 256) s += bn_w[(size_t)o * 4096 + j] * o_b[j];
  for (int off = 32; off; off >>= 1) s += __shfl_xor(s, off);
  __shared__ float red[4];
  if ((t & 63) == 0) red[t >> 6] = s;
  __syncthreads();
  if (t == 0) {
    const float tot = red[0] + red[1] + red[2] + red[3];
    const float inv = g[o] * rsqrtf(v_[o] + 1e-5f);
    fbias[o] = inv * tot + bb[o] - m_[o] * inv;
  }
}

// jj in [0,18): (scale, col): 0->(1,0); 1..3->(3,j); 4..9->(6,j); 10..17->(8,j)
__device__ __forceinline__ void jj_to_range(int jj, int& s, int& j, int& c0, int& c1) {
  if (jj < 1)       { s = 1; j = jj; }
  else if (jj < 4)  { s = 3; j = jj - 1; }
  else if (jj < 10) { s = 6; j = jj - 4; }
  else              { s = 8; j = jj - 10; }
  c0 = (j * 64) / s;
  c1 = ((j + 1) * 64 + s - 1) / s;   // matches AdaptiveAvgPool2d
}

// Stage 1: pool along W. kvT [b][4096][512] bf16 -> cp [b][64][18][512] fp32 sums
__global__ __launch_bounds__(256) void pool_cols(const u16* __restrict__ kvT,
                                                 float* __restrict__ cp) {
  const int b = blockIdx.y, r = blockIdx.x, t = threadIdx.x;
  const u16* base = kvT + ((size_t)b * 4096 + (size_t)r * 64) * 512;
  const int ch0 = (t & 63) * 8;
  for (int jj = (t >> 6); jj < 18; jj += 4) {
    int s, j, c0, c1;
    jj_to_range(jj, s, j, c0, c1);
    float acc[8] = {0.f, 0.f, 0.f, 0.f, 0.f, 0.f, 0.f, 0.f};
    for (int c = c0; c < c1; ++c) {
      const s16x8 v = *reinterpret_cast<const s16x8*>(base + (size_t)c * 512 + ch0);
#pragma unroll
      for (int i = 0; i < 8; ++i) acc[i] += b2f((u16)v[i]);
    }
    float* o = cp + (((size_t)(b * 64 + r) * 18 + jj) * 512 + ch0);
    *reinterpret_cast<float4*>(o)     = make_float4(acc[0], acc[1], acc[2], acc[3]);
    *reinterpret_cast<float4*>(o + 4) = make_float4(acc[4], acc[5], acc[6], acc[7]);
  }
}

// Stage 2: pool along H. cp -> Kpool [b][128][256], VpoolT [b][256][128]
__global__ __launch_bounds__(256) void pool_rows(const float* __restrict__ cp,
    u16* __restrict__ Kp, u16* __restrict__ Vp) {
  const int b = blockIdx.y, m = blockIdx.x, t = threadIdx.x;
  if (m >= 110) {
    Kp[((size_t)b * 128 + m) * 256 + t] = 0;
    Vp[((size_t)b * 256 + t) * 128 + m] = 0;
    return;
  }
  int s, idx, jjbase;
  if (m < 1)       { s = 1; idx = m;      jjbase = 0; }
  else if (m < 10) { s = 3; idx = m - 1;  jjbase = 1; }
  else if (m < 46) { s = 6; idx = m - 10; jjbase = 4; }
  else             { s = 8; idx = m - 46; jjbase = 10; }
  const int i = idx / s, j = idx % s;
  const int jj = jjbase + j;
  const int r0 = (i * 64) / s, r1 = ((i + 1) * 64 + s - 1) / s;
  const int c0 = (j * 64) / s, c1 = ((j + 1) * 64 + s - 1) / s;
  float a0 = 0.f, a1 = 0.f;
  for (int r = r0; r < r1; ++r) {
    const float* px = cp + ((size_t)(b * 64 + r) * 18 + jj) * 512;
    a0 += px[t];
    a1 += px[t + 256];
  }
  const float inv = 1.f / (float)((r1 - r0) * (c1 - c0));
  Kp[((size_t)b * 128 + m) * 256 + t] = f2b(a0 * inv);
  Vp[((size_t)b * 256 + t) * 128 + m] = f2b(a1 * inv);
}

extern "C" void kernel_launch(void* const* d_in, const int* in_sizes, int n_in,
                              void* d_out, int out_size, void* d_ws, size_t ws_size,
                              hipStream_t stream) {
  (void)in_sizes; (void)n_in; (void)out_size; (void)ws_size;
  const float* low  = (const float*)d_in[0];
  const float* high = (const float*)d_in[1];
  const float* q_w = (const float*)d_in[2];
  const float* q_g = (const float*)d_in[3];
  const float* q_b = (const float*)d_in[4];
  const float* q_m = (const float*)d_in[5];
  const float* q_v = (const float*)d_in[6];
  const float* k_w = (const float*)d_in[7];
  const float* k_g = (const float*)d_in[8];
  const float* k_b = (const float*)d_in[9];
  const float* k_m = (const float*)d_in[10];
  const float* k_v = (const float*)d_in[11];
  const float* v_w = (const float*)d_in[12];
  const float* v_b = (const float*)d_in[13];
  const float* o_w = (const float*)d_in[14];
  const float* o_b = (const float*)d_in[15];
  const float* bn_w = (const float*)d_in[16];
  const float* bn_g = (const float*)d_in[17];
  const float* bn_b = (const float*)d_in[18];
  const float* bn_m = (const float*)d_in[19];
  const float* bn_v = (const float*)d_in[20];
  float* out = (float*)d_out;

  char* ws = (char*)d_ws;
  size_t off = 0;
  auto alloc = [&](size_t bytes) -> char* {
    char* p = ws + off;
    off += (bytes + 255) & ~(size_t)255;
    return p;
  };
  u16* XhT  = (u16*)alloc(134217728ull);  // [8][4096][2048] bf16
  u16* qT   = (u16*)alloc(16777216ull);   // [8][4096][256]  bf16   (bn1s overlay, earlier)
  u16* XlT  = (u16*)alloc(67108864ull);   // [8][4096][1024] bf16   (cp overlay, later)
  u16* kvT  = (u16*)alloc(33554432ull);   // [8][4096][512]  bf16
  u16* ctxT = (u16*)alloc(16777216ull);   // [8][4096][256]  bf16   (owT overlay, earlier)
  u16* Kpool = (u16*)alloc(524288ull);    // [8][128][256] bf16 (rows>=110 zeroed)
  u16* VpT   = (u16*)alloc(524288ull);    // [8][256][128] bf16 (cols>=110 zeroed)
  u16* Wq   = (u16*)alloc(1048576ull);    // [256][2048] bf16 (BN-folded)
  u16* Wkv  = (u16*)alloc(1048576ull);    // [512][1024] bf16 (k BN-folded | v)
  u16* Wfin = (u16*)alloc(9437184ull);    // [2048][2304] bf16 = [W_high | W_comb]
  float* qbias  = (float*)alloc(1024);
  float* kvbias = (float*)alloc(2048);
  float* fbias  = (float*)alloc(8192);
  // overlays (strictly ordered)
  u16* bn1s = qT;            // [2048][2048] bf16, dead after W_comb GEMM
  u16* owT  = ctxT;          // [256][2048] bf16, dead after W_comb GEMM
  float* cp  = (float*)((char*)XlT + 25165824ull);  // [8][64][18][512] fp32 (18.9MB) @ XlT+24MB

  // --- weight prep + o-proj/bottleneck fold ---
  prep_bn<<<16384, 256, 0, stream>>>(bn_w, bn_g, bn_v, bn1s, Wfin);
  prep_fbias<<<2048, 256, 0, stream>>>(bn_w, o_b, bn_g, bn_b, bn_m, bn_v, fbias);
  prep_wq<<<2048, 256, 0, stream>>>(q_w, q_g, q_b, q_m, q_v, Wq, qbias);
  prep_wkv<<<2048, 256, 0, stream>>>(k_w, k_g, k_b, k_m, k_v, v_w, v_b, Wkv, kvbias);
  transpose_cvt<<<dim3(4, 32, 1), 256, 0, stream>>>(o_w, owT, 2048, 256);
  // W_comb = (inv*bn_w1) @ o_w  -> Wfin cols 2048..2303
  gemm_bt<1><<<dim3(16, 2, 1), 256, 0, stream>>>(
      bn1s, 0, 2048, owT, 0, 2048, (const u16*)0, 0, 0,
      (void*)(Wfin + 2048), 0, 2304, (const float*)0, 0, 0, 1.0f);

  // --- activation transpose+convert ---
  transpose_cvt<<<dim3(64, 32, 8), 256, 0, stream>>>(high, XhT, 2048, 4096);
  transpose_cvt<<<dim3(64, 16, 8), 256, 0, stream>>>(low, XlT, 1024, 4096);

  // --- q = relu(bnfold(qw) @ Xh) ; qT [b][4096][256] ---
  gemm_bt<1><<<dim3(32, 2, 8), 256, 0, stream>>>(
      XhT, 4096ll * 2048, 2048, Wq, 0, 2048, (const u16*)0, 0, 0,
      qT, 4096ll * 256, 256, qbias, 1, 256, 1.0f);
  // --- kv stacked (2-phase 256^2, 2 blocks/CU): cols<256 relu'd k, else v ---
  gemm256<1><<<dim3(16, 2, 8), 512, 0, stream>>>(
      XlT, 4096ll * 1024, 1024, Wkv, 0, 1024, (const u16*)0, 0, 0,
      kvT, 4096ll * 512, 512, kvbias, 1, 256, 1.0f);
  // --- PPM pool (separable: W then H) ---
  pool_cols<<<dim3(64, 8), 256, 0, stream>>>(kvT, cp);
  pool_rows<<<dim3(128, 8), 256, 0, stream>>>(cp, Kpool, VpT);
  // --- fused attention: sim + softmax + PV -> ctxT ---
  attn_fused<<<dim3(32, 8), 512, 0, stream>>>(qT, Kpool, VpT, ctxT);
  // --- out = Wfin @ [Xh ; ctx] + fbias (2-phase 256^2, 2 blocks/CU) ---
  gemm256<0><<<dim3(8, 16, 8), 512, 0, stream>>>(
      Wfin, 0, 2304, XhT, 4096ll * 2048, 2048, ctxT, 4096ll * 256, 256,
      out, 2048ll * 4096, 4096, fbias, 2, 0, 1.0f);
}

// Round 12
// 735.797 us; speedup vs baseline: 5.2095x; 5.2095x over previous
//
#include <hip/hip_runtime.h>
#include <hip/hip_bf16.h>

typedef unsigned int u32;
typedef unsigned short u16;
typedef short s16x8 __attribute__((ext_vector_type(8)));   // 8 bf16 (4 VGPR) MFMA A/B frag
typedef float f32x4 __attribute__((ext_vector_type(4)));   // MFMA acc
typedef u16 u16x4 __attribute__((ext_vector_type(4)));

__device__ __forceinline__ u16 f2b(float x) {              // RTNE fp32->bf16
  u32 u = __float_as_uint(x);
  return (u16)((u + 0x7fffu + ((u >> 16) & 1u)) >> 16);
}
__device__ __forceinline__ float b2f(u16 x) { return __uint_as_float(((u32)x) << 16); }

__device__ __forceinline__ void gload16(const void* g, void* l) {
  __builtin_amdgcn_global_load_lds((const __attribute__((address_space(1))) u32*)g,
                                   (__attribute__((address_space(3))) u32*)l, 16, 0, 0);
}
__device__ __forceinline__ f32x4 mfma16(s16x8 a, s16x8 b, f32x4 c) {
  return __builtin_amdgcn_mfma_f32_16x16x32_bf16(a, b, c, 0, 0, 0);
}

// ---------------------------------------------------------------------------
// gemm256 v5 (frozen best — round-9 exact): 256x256 tile, BK=64, 8 waves
// (2Mx4N), 128KiB LDS dbuf, quarter-granular A staging, counted vmcnt(6),
// XOR swizzle (T2, 0 conflicts), setprio (T5), XCD remap (T1).
// launch_bounds(512,2): this tile's acc[8][4]=128 VGPR makes 4 waves/EU
// impossible (round 11: forcing it spilled acc -> 6 GB scratch, 9x slower).
// WAR ledger verified round 7.
// ---------------------------------------------------------------------------
template <int OUT_BF16>
__global__ __launch_bounds__(512, 2) void gemm256(
    const u16* __restrict__ A, long long sA, int lda,
    const u16* __restrict__ B1, long long sB1, int K1,
    const u16* __restrict__ B2, long long sB2, int K2,
    void* __restrict__ Cv, long long sC, int ldc,
    const float* __restrict__ bias, int bias_mode,  // 0 none, 1 per-col, 2 per-row
    int relu_limit, float alpha) {
  const int K = K1 + K2, nt = K >> 6;
  int tm, tn, b;
  {
    const int flat = blockIdx.x + gridDim.x * (blockIdx.y + gridDim.y * blockIdx.z);
    if (gridDim.z == 8) {
      const int slot = flat >> 3;
      b = flat & 7;
      tm = slot % gridDim.x;
      tn = slot / gridDim.x;
    } else { tm = blockIdx.x; tn = blockIdx.y; b = blockIdx.z; }
  }
  const u16* Ab = A + (size_t)b * sA + (size_t)tm * 256 * lda;
  const u16* B1b = B1 + (size_t)b * sB1 + (size_t)tn * 256 * K1;
  const u16* B2b = B2 ? (B2 + (size_t)b * sB2 + (size_t)tn * 256 * K2) : (const u16*)0;

  __shared__ __attribute__((aligned(128))) char lds[131072];  // 2 x (A 32KB | B 32KB)

  const int tt = threadIdx.x, w = tt >> 6, l = tt & 63;
  const int wr = w >> 2, wc = w & 3;
  const int lr = l & 15, g16 = l >> 4;
  const int sxl = (lr & 7) << 4;

  auto stage_Aq = [&](int kt, int q) {
    const int bufB = (kt & 1) << 16;
    const int kk = kt << 6;
    const int lin = tt << 4;
    const int x = lin ^ (((lin >> 7) & 7) << 4);
    gload16(Ab + (size_t)((q << 6) + (x >> 7)) * lda + kk + ((x & 127) >> 1),
            lds + bufB + (q << 13) + (w << 10));
  };
  auto stage_Bh = [&](int kt, int h) {
    const int bufB = (kt & 1) << 16;
    const int kk = kt << 6;
    const u16* src; int ld, kcol;
    if (kk < K1) { src = B1b; ld = K1; kcol = kk; }
    else         { src = B2b; ld = K2; kcol = kk - K1; }
#pragma unroll
    for (int g = 0; g < 2; ++g) {
      const int lin = (g << 13) | (tt << 4);
      const int x = lin ^ (((lin >> 7) & 7) << 4);
      gload16(src + (size_t)((h << 7) + (x >> 7)) * ld + kcol + ((x & 127) >> 1),
              lds + bufB + 32768 + (h << 14) + (g << 13) + (w << 10));
    }
  };

  auto lda_frag = [&](const char* Al, int h, int kk, s16x8* af) {
#pragma unroll
    for (int i = 0; i < 4; ++i) {
      const int row = wr * 128 + (h * 4 + i) * 16 + lr;
      af[i] = *reinterpret_cast<const s16x8*>(
          Al + (row << 7) + (((kk << 6) | (g16 << 4)) ^ sxl));
    }
  };
  auto ldb_frag = [&](const char* Bl, int kk, s16x8* bf) {
#pragma unroll
    for (int n = 0; n < 4; ++n) {
      const int row = wc * 64 + n * 16 + lr;
      bf[n] = *reinterpret_cast<const s16x8*>(
          Bl + (row << 7) + (((kk << 6) | (g16 << 4)) ^ sxl));
    }
  };

  f32x4 acc[8][4] = {};

  auto mfma_q = [&](int h, const s16x8* af, const s16x8* bf) {
    __builtin_amdgcn_s_setprio(1);
#pragma unroll
    for (int i = 0; i < 4; ++i)
#pragma unroll
      for (int n = 0; n < 4; ++n)
        acc[h * 4 + i][n] = mfma16(af[i], bf[n], acc[h * 4 + i][n]);
    __builtin_amdgcn_s_setprio(0);
  };

  stage_Aq(0, 0); stage_Aq(0, 2); stage_Bh(0, 0); stage_Bh(0, 1);
  stage_Aq(0, 1); stage_Aq(0, 3);
  if (nt > 1) {
    stage_Aq(1, 0); stage_Aq(1, 2); stage_Bh(1, 0); stage_Bh(1, 1);
    asm volatile("s_waitcnt vmcnt(6)" ::: "memory");
  } else {
    asm volatile("s_waitcnt vmcnt(0)" ::: "memory");
  }
  __builtin_amdgcn_s_barrier();

  for (int t = 0; t < nt; ++t) {
    const char* Al = lds + ((t & 1) << 16);
    const char* Bl = Al + 32768;
    s16x8 bf0[4], bf1[4], af[4];

    lda_frag(Al, 0, 0, af);
    ldb_frag(Bl, 0, bf0);
    if (t + 1 < nt) { stage_Aq(t + 1, 1); stage_Aq(t + 1, 3); }
    __builtin_amdgcn_s_barrier();
    asm volatile("s_waitcnt lgkmcnt(0)" ::: "memory");
    mfma_q(0, af, bf0);
    __builtin_amdgcn_s_barrier();

    lda_frag(Al, 0, 1, af);
    ldb_frag(Bl, 1, bf1);
    __builtin_amdgcn_s_barrier();
    asm volatile("s_waitcnt lgkmcnt(0)" ::: "memory");
    mfma_q(0, af, bf1);
    __builtin_amdgcn_s_barrier();

    lda_frag(Al, 1, 0, af);
    if (t + 2 < nt) { stage_Aq(t + 2, 0); stage_Aq(t + 2, 2); stage_Bh(t + 2, 0); }
    __builtin_amdgcn_s_barrier();
    asm volatile("s_waitcnt lgkmcnt(0)" ::: "memory");
    mfma_q(1, af, bf0);
    __builtin_amdgcn_s_barrier();

    lda_frag(Al, 1, 1, af);
    if (t + 2 < nt) stage_Bh(t + 2, 1);
    __builtin_amdgcn_s_barrier();
    asm volatile("s_waitcnt lgkmcnt(0)" ::: "memory");
    mfma_q(1, af, bf1);
    if (t + 1 < nt) {
      if (t + 2 < nt) asm volatile("s_waitcnt vmcnt(6)" ::: "memory");
      else            asm volatile("s_waitcnt vmcnt(0)" ::: "memory");
    }
    __builtin_amdgcn_s_barrier();
  }

  const int li = g16 * 4;
#pragma unroll
  for (int m = 0; m < 8; ++m) {
    const int row = tm * 256 + wr * 128 + m * 16 + li;
#pragma unroll
    for (int j = 0; j < 4; ++j) {
      const int col = tn * 256 + wc * 64 + j * 16 + lr;
      const float bc = (bias_mode == 1) ? bias[col] : 0.f;
#pragma unroll
      for (int i = 0; i < 4; ++i) {
        float v = acc[m][j][i] * alpha;
        v += (bias_mode == 2) ? bias[row + i] : bc;
        if (col < relu_limit) v = fmaxf(v, 0.f);
        const size_t idx = (size_t)b * sC + (size_t)(row + i) * ldc + col;
        if (OUT_BF16) ((u16*)Cv)[idx] = f2b(v);
        else          ((float*)Cv)[idx] = v;
      }
    }
  }
}

// ---------------------------------------------------------------------------
// m97-structure 128x128 GEMM (W_comb only).
// ---------------------------------------------------------------------------
template <int OUT_BF16>
__global__ __launch_bounds__(256) void gemm_bt(
    const u16* __restrict__ A, long long sA, int lda,
    const u16* __restrict__ B1, long long sB1, int K1,
    const u16* __restrict__ B2, long long sB2, int K2,
    void* __restrict__ Cv, long long sC, int ldc,
    const float* __restrict__ bias, int bias_mode,
    int relu_limit, float alpha) {
  const int K = K1 + K2;
  const int b = blockIdx.z;
  const int tm = blockIdx.x, tn = blockIdx.y;
  const u16* Ab = A + (size_t)b * sA;
  const u16* B1b = B1 + (size_t)b * sB1;
  const u16* B2b = B2 ? (B2 + (size_t)b * sB2) : (const u16*)0;

  __shared__ u16 As[128 * 32];
  __shared__ u16 Bs[128 * 32];

  const int t = threadIdx.x;
  const int w = t >> 6, l = t & 63;
  const int wr = w >> 1, wc = w & 1;
  const int srow = w * 16 + (l >> 2);
  const int scol = (l & 3) * 8;
  u16* AsW = As + w * 512;
  u16* BsW = Bs + w * 512;

  f32x4 acc[4][4] = {};
  const int lr = l & 15, lk = (l >> 4) * 8;

  for (int kk = 0; kk < K; kk += 32) {
    __syncthreads();
    {
      const u16* g0 = Ab + (size_t)(tm * 128 + srow) * lda + (kk + scol);
      gload16(g0, AsW);
      gload16(g0 + (size_t)64 * lda, AsW + 2048);
    }
    {
      const u16* bb; int ld, kloc;
      if (kk < K1) { bb = B1b; ld = K1; kloc = kk; }
      else         { bb = B2b; ld = K2; kloc = kk - K1; }
      const u16* g0 = bb + (size_t)(tn * 128 + srow) * ld + (kloc + scol);
      gload16(g0, BsW);
      gload16(g0 + (size_t)64 * ld, BsW + 2048);
    }
    __syncthreads();
    s16x8 af[4], bfr[4];
#pragma unroll
    for (int m = 0; m < 4; ++m)
      af[m] = *reinterpret_cast<const s16x8*>(&As[(wr * 64 + m * 16 + lr) * 32 + lk]);
#pragma unroll
    for (int j = 0; j < 4; ++j)
      bfr[j] = *reinterpret_cast<const s16x8*>(&Bs[(wc * 64 + j * 16 + lr) * 32 + lk]);
#pragma unroll
    for (int m = 0; m < 4; ++m)
#pragma unroll
      for (int j = 0; j < 4; ++j)
        acc[m][j] = mfma16(af[m], bfr[j], acc[m][j]);
  }

  const int li = (l >> 4) * 4;
#pragma unroll
  for (int m = 0; m < 4; ++m) {
    const int row = tm * 128 + wr * 64 + m * 16 + li;
#pragma unroll
    for (int j = 0; j < 4; ++j) {
      const int col = tn * 128 + wc * 64 + j * 16 + lr;
      const float bc = (bias_mode == 1) ? bias[col] : 0.f;
#pragma unroll
      for (int i = 0; i < 4; ++i) {
        float v = acc[m][j][i] * alpha;
        v += (bias_mode == 2) ? bias[row + i] : bc;
        if (col < relu_limit) v = fmaxf(v, 0.f);
        const size_t idx = (size_t)b * sC + (size_t)(row + i) * ldc + col;
        if (OUT_BF16) ((u16*)Cv)[idx] = f2b(v);
        else          ((float*)Cv)[idx] = v;
      }
    }
  }
}

// ---------------------------------------------------------------------------
// attn_fused: sim + softmax + PV in one kernel (verified round 9).
// ---------------------------------------------------------------------------
__global__ __launch_bounds__(512) void attn_fused(
    const u16* __restrict__ qT,   // [8][4096][256] bf16
    const u16* __restrict__ Kp,   // [8][128][256] bf16 (rows>=110 zero)
    const u16* __restrict__ Vp,   // [8][256][128] bf16
    u16* __restrict__ ctxT) {     // [8][4096][256] bf16
  const int qb = blockIdx.x, b = blockIdx.y;
  const int tt = threadIdx.x, w = tt >> 6, l = tt & 63;
  const int lr = l & 15, hi = l >> 4;
  __shared__ __attribute__((aligned(128))) char lds[131072];

  const char* KpG = (const char*)(Kp + (size_t)b * 32768);
  const char* VpG = (const char*)(Vp + (size_t)b * 32768);
#pragma unroll
  for (int g = 0; g < 8; ++g) {
    const int lin = (g * 512 + tt) << 4;
    gload16(KpG + (lin ^ (((lin >> 9) & 7) << 4)), lds + g * 8192 + w * 1024);
  }
#pragma unroll
  for (int g = 0; g < 8; ++g) {
    const int lin = (g * 512 + tt) << 4;
    gload16(VpG + (lin ^ (((lin >> 8) & 7) << 4)), lds + 65536 + g * 8192 + w * 1024);
  }

  const u16* qG = qT + ((size_t)b * 4096 + qb * 128 + w * 16 + lr) * 256 + hi * 8;
  s16x8 qf[8];
#pragma unroll
  for (int kk = 0; kk < 8; ++kk)
    qf[kk] = *reinterpret_cast<const s16x8*>(qG + kk * 32);

  asm volatile("s_waitcnt vmcnt(0)" ::: "memory");
  __syncthreads();

  f32x4 ps[8] = {};
  for (int kk = 0; kk < 8; ++kk) {
#pragma unroll
    for (int j = 0; j < 8; ++j) {
      const int y = (j * 16 + lr) * 512 + kk * 64 + hi * 16;
      const s16x8 kf = *reinterpret_cast<const s16x8*>(lds + (y ^ (((y >> 9) & 7) << 4)));
      ps[j] = mfma16(qf[kk], kf, ps[j]);
    }
  }
  __syncthreads();   // all waves done reading Kp region before P overwrites it

#pragma unroll
  for (int i = 0; i < 4; ++i) {
    float m0 = -1e30f;
#pragma unroll
    for (int j = 0; j < 7; ++j) {
      float v = ps[j][i] * 0.0625f;
      if (j == 6 && lr >= 14) v = -1e30f;
      m0 = fmaxf(m0, v);
    }
#pragma unroll
    for (int off = 8; off; off >>= 1) m0 = fmaxf(m0, __shfl_xor(m0, off, 16));
    float s0 = 0.f;
#pragma unroll
    for (int j = 0; j < 7; ++j) {
      const float v = ps[j][i] * 0.0625f;
      const float ev = (j == 6 && lr >= 14) ? 0.f : __expf(v - m0);
      ps[j][i] = ev;
      s0 += ev;
    }
    ps[7][i] = 0.f;
#pragma unroll
    for (int off = 8; off; off >>= 1) s0 += __shfl_xor(s0, off, 16);
    const float inv = 1.f / s0;
#pragma unroll
    for (int j = 0; j < 8; ++j) ps[j][i] *= inv;
  }

  char* PL = lds + w * 4096;
#pragma unroll
  for (int j = 0; j < 8; ++j)
#pragma unroll
    for (int i = 0; i < 4; ++i) {
      const int n = hi * 4 + i, m = j * 16 + lr;
      const int y = n * 256 + m * 2;
      *reinterpret_cast<u16*>(PL + (y ^ ((n & 7) << 4))) = f2b(ps[j][i]);
    }
  __syncthreads();

  f32x4 pc[16] = {};
  const char* VL = lds + 65536;
#pragma unroll
  for (int kk = 0; kk < 4; ++kk) {
    const int ya = lr * 256 + kk * 64 + hi * 16;
    const s16x8 pa = *reinterpret_cast<const s16x8*>(PL + (ya ^ ((lr & 7) << 4)));
#pragma unroll
    for (int jc = 0; jc < 16; ++jc) {
      const int y = (jc * 16 + lr) * 256 + kk * 64 + hi * 16;
      const s16x8 vf = *reinterpret_cast<const s16x8*>(VL + (y ^ (((y >> 8) & 7) << 4)));
      pc[jc] = mfma16(pa, vf, pc[jc]);
    }
  }

  u16* outp = ctxT + ((size_t)b * 4096 + qb * 128 + w * 16) * 256;
#pragma unroll
  for (int jc = 0; jc < 16; ++jc)
#pragma unroll
    for (int i = 0; i < 4; ++i)
      outp[(size_t)(hi * 4 + i) * 256 + jc * 16 + lr] = f2b(pc[jc][i]);
}

// [b][R][C] fp32 -> [b][C][R] bf16 ; R,C multiples of 64
__global__ __launch_bounds__(256) void transpose_cvt(
    const float* __restrict__ in, u16* __restrict__ out, int R, int C) {
  const int b = blockIdx.z;
  in += (size_t)b * R * C;
  out += (size_t)b * R * C;
  const int ct = blockIdx.x, rt = blockIdx.y;
  __shared__ float tile[64][65];
  const int t = threadIdx.x;
  {
    const int c4 = (t & 15) * 4, r0 = t >> 4;
    const float* src = in + (size_t)(rt * 64 + r0) * C + ct * 64 + c4;
#pragma unroll
    for (int i = 0; i < 4; ++i) {
      const float4 v = *reinterpret_cast<const float4*>(src + (size_t)(i * 16) * C);
      tile[r0 + i * 16][c4 + 0] = v.x; tile[r0 + i * 16][c4 + 1] = v.y;
      tile[r0 + i * 16][c4 + 2] = v.z; tile[r0 + i * 16][c4 + 3] = v.w;
    }
  }
  __syncthreads();
  {
    const int r4 = (t & 15) * 4, c0 = t >> 4;
    u16* dst = out + (size_t)(ct * 64 + c0) * R + rt * 64 + r4;
#pragma unroll
    for (int i = 0; i < 4; ++i) {
      u16x4 o;
      o.x = f2b(tile[r4 + 0][c0 + i * 16]);
      o.y = f2b(tile[r4 + 1][c0 + i * 16]);
      o.z = f2b(tile[r4 + 2][c0 + i * 16]);
      o.w = f2b(tile[r4 + 3][c0 + i * 16]);
      *reinterpret_cast<u16x4*>(dst + (size_t)(i * 16) * R) = o;
    }
  }
}

// folded-BN weight preps -------------------------------------------------------
__global__ __launch_bounds__(256) void prep_wq(const float* __restrict__ qw,
    const float* __restrict__ qg, const float* __restrict__ qb_,
    const float* __restrict__ qm, const float* __restrict__ qv,
    u16* __restrict__ Wq, float* __restrict__ qbias) {
  const int i = blockIdx.x * 256 + threadIdx.x;  // 256*2048
  const int o = i >> 11, c = i & 2047;
  const float inv = qg[o] * rsqrtf(qv[o] + 1e-5f);
  Wq[i] = f2b(qw[i] * inv);
  if (c == 0) qbias[o] = qb_[o] - qm[o] * inv;
}

__global__ __launch_bounds__(256) void prep_wkv(const float* __restrict__ kw,
    const float* __restrict__ kg, const float* __restrict__ kb,
    const float* __restrict__ km, const float* __restrict__ kv,
    const float* __restrict__ vw, const float* __restrict__ vb,
    u16* __restrict__ Wkv, float* __restrict__ kvbias) {
  const int i = blockIdx.x * 256 + threadIdx.x;  // 512*1024
  const int r = i >> 10, c = i & 1023;
  if (r < 256) {
    const float inv = kg[r] * rsqrtf(kv[r] + 1e-5f);
    Wkv[i] = f2b(kw[i] * inv);
    if (c == 0) kvbias[r] = kb[r] - km[r] * inv;
  } else {
    Wkv[i] = f2b(vw[(size_t)(r - 256) * 1024 + c]);
    if (c == 0) kvbias[r] = vb[r - 256];
  }
}

__global__ __launch_bounds__(256) void prep_bn(const float* __restrict__ bn_w,
    const float* __restrict__ g, const float* __restrict__ v_,
    u16* __restrict__ bn1s, u16* __restrict__ Wfin) {
  const int i = blockIdx.x * 256 + threadIdx.x;  // 2048*2048
  const int o = i >> 11, j = i & 2047;
  const float inv = g[o] * rsqrtf(v_[o] + 1e-5f);
  bn1s[i] = f2b(bn_w[(size_t)o * 4096 + j] * inv);
  Wfin[(size_t)o * 2304 + j] = f2b(bn_w[(size_t)o * 4096 + 2048 + j] * inv);
}

__global__ __launch_bounds__(256) void prep_fbias(const float* __restrict__ bn_w,
    const float* __restrict__ o_b, const float* __restrict__ g,
    const float* __restrict__ bb, const float* __restrict__ m_,
    const float* __restrict__ v_, float* __restrict__ fbias) {
  const int o = blockIdx.x, t = threadIdx.x;
  float s = 0.f;
  for (int j = t; j < 2048; j += 256) s += bn_w[(size_t)o * 4096 + j] * o_b[j];
  for (int off = 32; off; off >>= 1) s += __shfl_xor(s, off);
  __shared__ float red[4];
  if ((t & 63) == 0) red[t >> 6] = s;
  __syncthreads();
  if (t == 0) {
    const float tot = red[0] + red[1] + red[2] + red[3];
    const float inv = g[o] * rsqrtf(v_[o] + 1e-5f);
    fbias[o] = inv * tot + bb[o] - m_[o] * inv;
  }
}

// jj in [0,18): (scale, col): 0->(1,0); 1..3->(3,j); 4..9->(6,j); 10..17->(8,j)
__device__ __forceinline__ void jj_to_range(int jj, int& s, int& j, int& c0, int& c1) {
  if (jj < 1)       { s = 1; j = jj; }
  else if (jj < 4)  { s = 3; j = jj - 1; }
  else if (jj < 10) { s = 6; j = jj - 4; }
  else              { s = 8; j = jj - 10; }
  c0 = (j * 64) / s;
  c1 = ((j + 1) * 64 + s - 1) / s;   // matches AdaptiveAvgPool2d
}

// Stage 1: pool along W. kvT [b][4096][512] bf16 -> cp [b][64][18][512] fp32 sums
__global__ __launch_bounds__(256) void pool_cols(const u16* __restrict__ kvT,
                                                 float* __restrict__ cp) {
  const int b = blockIdx.y, r = blockIdx.x, t = threadIdx.x;
  const u16* base = kvT + ((size_t)b * 4096 + (size_t)r * 64) * 512;
  const int ch0 = (t & 63) * 8;
  for (int jj = (t >> 6); jj < 18; jj += 4) {
    int s, j, c0, c1;
    jj_to_range(jj, s, j, c0, c1);
    float acc[8] = {0.f, 0.f, 0.f, 0.f, 0.f, 0.f, 0.f, 0.f};
    for (int c = c0; c < c1; ++c) {
      const s16x8 v = *reinterpret_cast<const s16x8*>(base + (size_t)c * 512 + ch0);
#pragma unroll
      for (int i = 0; i < 8; ++i) acc[i] += b2f((u16)v[i]);
    }
    float* o = cp + (((size_t)(b * 64 + r) * 18 + jj) * 512 + ch0);
    *reinterpret_cast<float4*>(o)     = make_float4(acc[0], acc[1], acc[2], acc[3]);
    *reinterpret_cast<float4*>(o + 4) = make_float4(acc[4], acc[5], acc[6], acc[7]);
  }
}

// Stage 2: pool along H. cp -> Kpool [b][128][256], VpoolT [b][256][128]
__global__ __launch_bounds__(256) void pool_rows(const float* __restrict__ cp,
    u16* __restrict__ Kp, u16* __restrict__ Vp) {
  const int b = blockIdx.y, m = blockIdx.x, t = threadIdx.x;
  if (m >= 110) {
    Kp[((size_t)b * 128 + m) * 256 + t] = 0;
    Vp[((size_t)b * 256 + t) * 128 + m] = 0;
    return;
  }
  int s, idx, jjbase;
  if (m < 1)       { s = 1; idx = m;      jjbase = 0; }
  else if (m < 10) { s = 3; idx = m - 1;  jjbase = 1; }
  else if (m < 46) { s = 6; idx = m - 10; jjbase = 4; }
  else             { s = 8; idx = m - 46; jjbase = 10; }
  const int i = idx / s, j = idx % s;
  const int jj = jjbase + j;
  const int r0 = (i * 64) / s, r1 = ((i + 1) * 64 + s - 1) / s;
  const int c0 = (j * 64) / s, c1 = ((j + 1) * 64 + s - 1) / s;
  float a0 = 0.f, a1 = 0.f;
  for (int r = r0; r < r1; ++r) {
    const float* px = cp + ((size_t)(b * 64 + r) * 18 + jj) * 512;
    a0 += px[t];
    a1 += px[t + 256];
  }
  const float inv = 1.f / (float)((r1 - r0) * (c1 - c0));
  Kp[((size_t)b * 128 + m) * 256 + t] = f2b(a0 * inv);
  Vp[((size_t)b * 256 + t) * 128 + m] = f2b(a1 * inv);
}

extern "C" void kernel_launch(void* const* d_in, const int* in_sizes, int n_in,
                              void* d_out, int out_size, void* d_ws, size_t ws_size,
                              hipStream_t stream) {
  (void)in_sizes; (void)n_in; (void)out_size; (void)ws_size;
  const float* low  = (const float*)d_in[0];
  const float* high = (const float*)d_in[1];
  const float* q_w = (const float*)d_in[2];
  const float* q_g = (const float*)d_in[3];
  const float* q_b = (const float*)d_in[4];
  const float* q_m = (const float*)d_in[5];
  const float* q_v = (const float*)d_in[6];
  const float* k_w = (const float*)d_in[7];
  const float* k_g = (const float*)d_in[8];
  const float* k_b = (const float*)d_in[9];
  const float* k_m = (const float*)d_in[10];
  const float* k_v = (const float*)d_in[11];
  const float* v_w = (const float*)d_in[12];
  const float* v_b = (const float*)d_in[13];
  const float* o_w = (const float*)d_in[14];
  const float* o_b = (const float*)d_in[15];
  const float* bn_w = (const float*)d_in[16];
  const float* bn_g = (const float*)d_in[17];
  const float* bn_b = (const float*)d_in[18];
  const float* bn_m = (const float*)d_in[19];
  const float* bn_v = (const float*)d_in[20];
  float* out = (float*)d_out;

  char* ws = (char*)d_ws;
  size_t off = 0;
  auto alloc = [&](size_t bytes) -> char* {
    char* p = ws + off;
    off += (bytes + 255) & ~(size_t)255;
    return p;
  };
  u16* XhT  = (u16*)alloc(134217728ull);  // [8][4096][2048] bf16
  u16* qT   = (u16*)alloc(16777216ull);   // [8][4096][256]  bf16   (bn1s overlay, earlier)
  u16* XlT  = (u16*)alloc(67108864ull);   // [8][4096][1024] bf16   (cp overlay, later)
  u16* kvT  = (u16*)alloc(33554432ull);   // [8][4096][512]  bf16
  u16* ctxT = (u16*)alloc(16777216ull);   // [8][4096][256]  bf16   (owT overlay, earlier)
  u16* Kpool = (u16*)alloc(524288ull);    // [8][128][256] bf16 (rows>=110 zeroed)
  u16* VpT   = (u16*)alloc(524288ull);    // [8][256][128] bf16 (cols>=110 zeroed)
  u16* Wq   = (u16*)alloc(1048576ull);    // [256][2048] bf16 (BN-folded)
  u16* Wkv  = (u16*)alloc(1048576ull);    // [512][1024] bf16 (k BN-folded | v)
  u16* Wfin = (u16*)alloc(9437184ull);    // [2048][2304] bf16 = [W_high | W_comb]
  float* qbias  = (float*)alloc(1024);
  float* kvbias = (float*)alloc(2048);
  float* fbias  = (float*)alloc(8192);
  // overlays (strictly ordered)
  u16* bn1s = qT;            // [2048][2048] bf16, dead after W_comb GEMM
  u16* owT  = ctxT;          // [256][2048] bf16, dead after W_comb GEMM
  float* cp  = (float*)((char*)XlT + 25165824ull);  // [8][64][18][512] fp32 (18.9MB) @ XlT+24MB

  // --- weight prep + o-proj/bottleneck fold ---
  prep_bn<<<16384, 256, 0, stream>>>(bn_w, bn_g, bn_v, bn1s, Wfin);
  prep_fbias<<<2048, 256, 0, stream>>>(bn_w, o_b, bn_g, bn_b, bn_m, bn_v, fbias);
  prep_wq<<<2048, 256, 0, stream>>>(q_w, q_g, q_b, q_m, q_v, Wq, qbias);
  prep_wkv<<<2048, 256, 0, stream>>>(k_w, k_g, k_b, k_m, k_v, v_w, v_b, Wkv, kvbias);
  transpose_cvt<<<dim3(4, 32, 1), 256, 0, stream>>>(o_w, owT, 2048, 256);
  // W_comb = (inv*bn_w1) @ o_w  -> Wfin cols 2048..2303
  gemm_bt<1><<<dim3(16, 2, 1), 256, 0, stream>>>(
      bn1s, 0, 2048, owT, 0, 2048, (const u16*)0, 0, 0,
      (void*)(Wfin + 2048), 0, 2304, (const float*)0, 0, 0, 1.0f);

  // --- activation transpose+convert ---
  transpose_cvt<<<dim3(64, 32, 8), 256, 0, stream>>>(high, XhT, 2048, 4096);
  transpose_cvt<<<dim3(64, 16, 8), 256, 0, stream>>>(low, XlT, 1024, 4096);

  // --- q = relu(bnfold(qw) @ Xh) ; qT [b][4096][256] (gemm256, N=256) ---
  gemm256<1><<<dim3(16, 1, 8), 512, 0, stream>>>(
      XhT, 4096ll * 2048, 2048, Wq, 0, 2048, (const u16*)0, 0, 0,
      qT, 4096ll * 256, 256, qbias, 1, 256, 1.0f);
  // --- kv stacked: cols<256 relu'd k, cols>=256 v ---
  gemm256<1><<<dim3(16, 2, 8), 512, 0, stream>>>(
      XlT, 4096ll * 1024, 1024, Wkv, 0, 1024, (const u16*)0, 0, 0,
      kvT, 4096ll * 512, 512, kvbias, 1, 256, 1.0f);
  // --- PPM pool (separable: W then H) ---
  pool_cols<<<dim3(64, 8), 256, 0, stream>>>(kvT, cp);
  pool_rows<<<dim3(128, 8), 256, 0, stream>>>(cp, Kpool, VpT);
  // --- fused attention: sim + softmax + PV -> ctxT ---
  attn_fused<<<dim3(32, 8), 512, 0, stream>>>(qT, Kpool, VpT, ctxT);
  // --- out = Wfin @ [Xh ; ctx] + fbias ; [b][2048][4096] fp32 NCHW ---
  gemm256<0><<<dim3(8, 16, 8), 512, 0, stream>>>(
      Wfin, 0, 2304, XhT, 4096ll * 2048, 2048, ctxT, 4096ll * 256, 256,
      out, 2048ll * 4096, 4096, fbias, 2, 0, 1.0f);
}